// Round 1
// baseline (1154.033 us; speedup 1.0000x reference)
//
#include <hip/hip_runtime.h>

// BatchedMonomialFactor: fused fp32 implementation.
// out[b, r*16+i] = sigmoid((x@W_alpha)[b,r,i]) * tanh((x@W_diag)[b,r,i]) *
//                  sum_{j: argmax_i' sinkhorn((x@W_perm)[b,r,:,:]*2)[i',j] == i} h[b,r,j]
//
// Precision note: forward output depends on soft_perm ONLY through a 16-way
// argmax (straight-through perm==hard in forward). Threshold = 2% of max|ref|,
// so argmax flips are fatal -> fp32 everywhere this round.

#define D_MODEL 1024
#define RDIM 64
#define BDIM 16
#define NBATCH 2048
#define MB 64      // batch rows per workgroup
#define KB 32      // K-step
#define XS_LD 68   // padded lds stride for x tile (16B-aligned rows, bank spread)

__global__ __launch_bounds__(256, 2)
void bmf_fused_kernel(const float* __restrict__ x,
                      const float* __restrict__ h,
                      const float* __restrict__ Wp,
                      const float* __restrict__ Wd,
                      const float* __restrict__ Wa,
                      float* __restrict__ out)
{
    // LDS: union of GEMM staging and sinkhorn scratch + persistent epilogue region
    __shared__ float sm[15488];                 // 61952 B
    float* xs   = sm;                           // [KB][XS_LD]  (2176)
    float* wsh  = sm + KB * XS_LD;              // [KB][256]    (8192)
    float* w2s  = wsh + KB * 256;               // [KB][32]     (1024)  total 11392
    float* la   = sm;                           // [32][16][17] (8704) — reuses GEMM region
    float* dval = sm + 11392;                   // [1024]
    float* aval = dval + 1024;                  // [1024]
    float* hv   = aval + 1024;                  // [1024]
    float* hpm  = hv + 1024;                    // [1024]

    const int t   = threadIdx.x;
    const int bid = blockIdx.x;
    const int r   = bid >> 5;                   // 0..63  (same-r blocks consecutive -> L2 reuse of Wp slice)
    const int bt  = bid & 31;                   // 0..31
    const int b0  = bt * MB;
    const long rcol0 = (long)r * (BDIM * BDIM); // col offset in Wp

    const int tr  = t >> 5;                     // 0..7 : row group (8 rows each)
    const int tc  = t & 31;                     // 0..31: col group
    const int cAi = tc * 4;                     // perm cols chunk A
    const int cBi = 128 + tc * 4;               // perm cols chunk B
    const int row2 = t >> 2;                    // 0..63 for diag/alpha part
    const int c2   = (t & 3) * 8;               // 0..24

    float acc[8][8];
    float acc2[8];
    #pragma unroll
    for (int i = 0; i < 8; i++) {
        acc2[i] = 0.f;
        #pragma unroll
        for (int j = 0; j < 8; j++) acc[i][j] = 0.f;
    }

    for (int ks = 0; ks < D_MODEL / KB; ++ks) {
        const int k0 = ks * KB;
        // ---- stage x tile (transposed into LDS) ----
        {
            const int row = t >> 2, kq = t & 3;
            #pragma unroll
            for (int e = 0; e < 2; e++) {
                const int kk = kq * 4 + e * 16;
                const float4 g = *(const float4*)(x + (long)(b0 + row) * D_MODEL + k0 + kk);
                xs[(kk + 0) * XS_LD + row] = g.x;
                xs[(kk + 1) * XS_LD + row] = g.y;
                xs[(kk + 2) * XS_LD + row] = g.z;
                xs[(kk + 3) * XS_LD + row] = g.w;
            }
        }
        // ---- stage W_perm tile [KB][256] ----
        {
            const int rbase = t >> 6;           // 0..3
            const int colf  = (t & 63) * 4;     // contiguous 1KB per wave
            #pragma unroll
            for (int rep = 0; rep < 8; rep++) {
                const int rowk = rbase + rep * 4;
                const float4 g = *(const float4*)(Wp + (long)(k0 + rowk) * (RDIM * BDIM * BDIM) + rcol0 + colf);
                *(float4*)(wsh + rowk * 256 + colf) = g;
            }
        }
        // ---- stage W_diag/W_alpha tile [KB][32] ----
        {
            const int kr = t >> 3;              // 0..31
            const int c  = (t & 7) * 4;         // 0..28
            const float* src = (c < 16)
                ? (Wd + (long)(k0 + kr) * D_MODEL + r * BDIM + c)
                : (Wa + (long)(k0 + kr) * D_MODEL + r * BDIM + (c - 16));
            const float4 g = *(const float4*)src;
            *(float4*)(w2s + kr * 32 + c) = g;
        }
        __syncthreads();
        // ---- compute ----
        #pragma unroll
        for (int kk = 0; kk < KB; ++kk) {
            const float4 xlo = *(const float4*)(xs + kk * XS_LD + tr * 8);
            const float4 xhi = *(const float4*)(xs + kk * XS_LD + tr * 8 + 4);
            const float4 wA  = *(const float4*)(wsh + kk * 256 + cAi);
            const float4 wB  = *(const float4*)(wsh + kk * 256 + cBi);
            const float xv[8] = {xlo.x, xlo.y, xlo.z, xlo.w, xhi.x, xhi.y, xhi.z, xhi.w};
            #pragma unroll
            for (int ri = 0; ri < 8; ri++) {
                acc[ri][0] += xv[ri] * wA.x; acc[ri][1] += xv[ri] * wA.y;
                acc[ri][2] += xv[ri] * wA.z; acc[ri][3] += xv[ri] * wA.w;
                acc[ri][4] += xv[ri] * wB.x; acc[ri][5] += xv[ri] * wB.y;
                acc[ri][6] += xv[ri] * wB.z; acc[ri][7] += xv[ri] * wB.w;
            }
            const float xv2 = xs[kk * XS_LD + row2];
            const float4 u0 = *(const float4*)(w2s + kk * 32 + c2);
            const float4 u1 = *(const float4*)(w2s + kk * 32 + c2 + 4);
            acc2[0] += xv2 * u0.x; acc2[1] += xv2 * u0.y;
            acc2[2] += xv2 * u0.z; acc2[3] += xv2 * u0.w;
            acc2[4] += xv2 * u1.x; acc2[5] += xv2 * u1.y;
            acc2[6] += xv2 * u1.z; acc2[7] += xv2 * u1.w;
        }
        __syncthreads();
    }

    // ---- persist diag/alpha pre-activations ----
    #pragma unroll
    for (int e = 0; e < 8; e++) {
        const int c = c2 + e;
        if (c < 16) dval[row2 * 16 + c] = acc2[e];
        else        aval[row2 * 16 + (c - 16)] = acc2[e];
    }
    // ---- stage h, zero h_permuted ----
    #pragma unroll
    for (int q = 0; q < 4; q++) {
        const int id  = t + 256 * q;
        const int row = id >> 4, j = id & 15;
        hv[id]  = h[(long)(b0 + row) * D_MODEL + r * BDIM + j];
        hpm[id] = 0.f;
    }
    __syncthreads();

    // ---- sinkhorn + argmax + scatter, two halves of 32 matrices ----
    for (int half = 0; half < 2; ++half) {
        if ((tr >> 2) == half) {                  // threads owning rows 32*half..+32
            const int mbase = (tr & 3) * 8;
            #pragma unroll
            for (int ri = 0; ri < 8; ri++) {
                const int m = mbase + ri;
                #pragma unroll
                for (int e = 0; e < 8; e++) {
                    const int col = (e < 4) ? (cAi + e) : (cBi + e - 4);
                    la[m * 272 + (col >> 4) * 17 + (col & 15)] = acc[ri][e] * 2.0f; // /TAU
                }
            }
        }
        __syncthreads();

        for (int it = 0; it < 5; ++it) {
            // row normalize (axis=-1: over j)
            #pragma unroll
            for (int q = 0; q < 2; q++) {
                const int id = t + 256 * q;
                const int m = id >> 4, i = id & 15;
                float* rowp = la + m * 272 + i * 17;
                float mx = rowp[0];
                #pragma unroll
                for (int j = 1; j < 16; j++) mx = fmaxf(mx, rowp[j]);
                float s = 0.f;
                #pragma unroll
                for (int j = 0; j < 16; j++) s += expf(rowp[j] - mx);
                const float lse = mx + logf(s);
                #pragma unroll
                for (int j = 0; j < 16; j++) rowp[j] -= lse;
            }
            __syncthreads();
            // col normalize (axis=-2: over i)
            #pragma unroll
            for (int q = 0; q < 2; q++) {
                const int id = t + 256 * q;
                const int m = id >> 4, j = id & 15;
                float* colp = la + m * 272 + j;
                float mx = colp[0];
                #pragma unroll
                for (int i = 1; i < 16; i++) mx = fmaxf(mx, colp[i * 17]);
                float s = 0.f;
                #pragma unroll
                for (int i = 0; i < 16; i++) s += expf(colp[i * 17] - mx);
                const float lse = mx + logf(s);
                #pragma unroll
                for (int i = 0; i < 16; i++) colp[i * 17] -= lse;
            }
            __syncthreads();
        }
        // argmax per column (first max, like jnp.argmax) + scatter h
        #pragma unroll
        for (int q = 0; q < 2; q++) {
            const int id = t + 256 * q;
            const int m = id >> 4, j = id & 15;
            const float* colp = la + m * 272 + j;
            float best = colp[0]; int bi = 0;
            #pragma unroll
            for (int i = 1; i < 16; i++) {
                const float v = colp[i * 17];
                if (v > best) { best = v; bi = i; }
            }
            const int gm = half * 32 + m;
            atomicAdd(&hpm[gm * 16 + bi], hv[gm * 16 + j]);
        }
        __syncthreads();
    }

    // ---- final: out = sigmoid(A) * tanh(D) * h_permuted ----
    #pragma unroll
    for (int q = 0; q < 4; q++) {
        const int id  = t + 256 * q;
        const int row = id >> 4, i = id & 15;
        const float A  = aval[id];
        const float Dv = dval[id];
        const float sg = 1.0f / (1.0f + expf(-A));
        out[(long)(b0 + row) * D_MODEL + r * BDIM + i] = sg * tanhf(Dv) * hpm[id];
    }
}

extern "C" void kernel_launch(void* const* d_in, const int* in_sizes, int n_in,
                              void* d_out, int out_size, void* d_ws, size_t ws_size,
                              hipStream_t stream) {
    const float* x  = (const float*)d_in[0];
    const float* h  = (const float*)d_in[1];
    const float* Wp = (const float*)d_in[2];
    const float* Wd = (const float*)d_in[3];
    const float* Wa = (const float*)d_in[4];
    float* out = (float*)d_out;
    // 64 r-blocks x 32 batch-tiles; same-r tiles consecutive for L2 reuse of Wp slice
    bmf_fused_kernel<<<dim3(RDIM * (NBATCH / MB)), dim3(256), 0, stream>>>(x, h, Wp, Wd, Wa, out);
}

// Round 2
// 595.164 us; speedup vs baseline: 1.9390x; 1.9390x over previous
//
#include <hip/hip_runtime.h>

// BatchedMonomialFactor round 2: bf16x3 split-GEMM on MFMA (fp32-faithful),
// fused sinkhorn/argmax/epilogue. Prep kernels split x,W into bf16 triples in
// d_ws each launch; host guard falls back to the round-1 fp32 kernel if ws is
// too small.

#define D_MODEL 1024
#define RDIM 64
#define BDIM 16
#define NBATCH 2048
#define MB 64
#define XS_LD 68

#define XSZ 2097152                    // 2048*1024 elements
#define WPSZ 16777216                  // 1024*16384
#define WDSZ 2097152                   // 1024*1024

// ws byte offsets
#define OFF_XS   0u
#define OFF_WPS  12582912u             // 3*XSZ*2
#define OFF_WDS  113246208u            // OFF_WPS + 3*WPSZ*2
#define OFF_WAS  121634816u            // OFF_WDS + 2*WDSZ*2
#define WS_NEED  130023424u            // OFF_WAS + 2*WDSZ*2

typedef __attribute__((ext_vector_type(8))) short short8;
typedef __attribute__((ext_vector_type(4))) float f32x4;
#define MFMA_BF16 __builtin_amdgcn_mfma_f32_16x16x32_bf16

__device__ __forceinline__ unsigned short f2bf_rne(float f) {
    unsigned u = __float_as_uint(f);
    unsigned r = (u + 0x7fffu + ((u >> 16) & 1u)) >> 16;
    return (unsigned short)r;
}
__device__ __forceinline__ float bf2f(unsigned short s) {
    return __uint_as_float(((unsigned)s) << 16);
}

// ---------------- prep: split x into 3 bf16 planes [s][b][k] ----------------
__global__ void k_split_x(const float* __restrict__ x, unsigned short* __restrict__ XS) {
    const int i = blockIdx.x * 256 + threadIdx.x;
    const float v = x[i];
    const unsigned short s1 = f2bf_rne(v);
    const float r1 = v - bf2f(s1);
    const unsigned short s2 = f2bf_rne(r1);
    const float r2 = r1 - bf2f(s2);
    const unsigned short s3 = f2bf_rne(r2);
    XS[i] = s1; XS[XSZ + i] = s2; XS[2 * XSZ + i] = s3;
}

// ---- prep: split W[k_global][c] -> dst[s][r][ks][n][k] (n=c%colsPerR) ------
__global__ void k_split_w(const float* __restrict__ W, unsigned short* __restrict__ dst,
                          int C, int colsPerR, int nSplits) {
    __shared__ float tile[32][65];
    const int t = threadIdx.x;
    const int c0 = blockIdx.x * 64;
    const int kt = blockIdx.y;
    #pragma unroll
    for (int i = 0; i < 8; i++) {
        const int k = (t >> 6) * 8 + i;
        tile[k][t & 63] = W[(long)(kt * 32 + k) * C + c0 + (t & 63)];
    }
    __syncthreads();
    const long sliceStride = (long)64 * 32 * colsPerR * 32;
    #pragma unroll
    for (int i = 0; i < 8; i++) {
        const int cl = (t >> 5) * 8 + i;
        const int c = c0 + cl;
        const int rr = c / colsPerR, nn = c % colsPerR;
        const int k = t & 31;
        const float v = tile[k][cl];
        const long off = (((long)(rr * 32 + kt) * colsPerR) + nn) * 32 + k;
        const unsigned short s1 = f2bf_rne(v);
        const float r1 = v - bf2f(s1);
        const unsigned short s2 = f2bf_rne(r1);
        dst[off] = s1;
        dst[sliceStride + off] = s2;
        if (nSplits == 3) {
            const float r2 = r1 - bf2f(s2);
            dst[2 * sliceStride + off] = f2bf_rne(r2);
        }
    }
}

// ---------------- main fused MFMA kernel ----------------
__global__ __launch_bounds__(256, 2)
void bmf_mfma_kernel(const unsigned short* __restrict__ XS,
                     const unsigned short* __restrict__ WPS,
                     const unsigned short* __restrict__ WDS,
                     const unsigned short* __restrict__ WAS,
                     const float* __restrict__ h,
                     float* __restrict__ out)
{
    __shared__ __align__(16) float sm[12800];     // 51200 B
    unsigned short* smA = (unsigned short*)sm;    // GEMM phase: [3][4][64][8] bf16 = 12288 B
    float* la   = sm;                             // sinkhorn: [32][16][17] = 8704 f (aliases smA)
    float* dval = sm + 8704;                      // [1024]
    float* aval = dval + 1024;
    float* hv   = aval + 1024;
    float* hpm  = hv + 1024;

    const int t   = threadIdx.x;
    const int l   = t & 63;
    const int w   = t >> 6;                       // wave 0..3
    const int bid = blockIdx.x;
    const int r   = bid >> 5;
    const int b0  = (bid & 31) * MB;
    const int quad = l >> 4, l15 = l & 15;

    f32x4 acc[4][4];                              // [mt][ntl]
    f32x4 acc2[2];
    #pragma unroll
    for (int a = 0; a < 4; a++)
        #pragma unroll
        for (int b = 0; b < 4; b++) acc[a][b] = (f32x4){0.f, 0.f, 0.f, 0.f};
    acc2[0] = (f32x4){0.f, 0.f, 0.f, 0.f};
    acc2[1] = (f32x4){0.f, 0.f, 0.f, 0.f};

    const int isAlpha = w >> 1;                   // waves 2,3 -> alpha
    const int mtPair  = w & 1;                    // this wave's acc2 mt pair: {2*mtPair, +1}
    const unsigned short* WX = isAlpha ? WAS : WDS;

    // staging indices
    const int srow = t >> 2;                      // 0..63
    const int skq  = t & 3;                       // 0..3
    // B-frag lane offset within a (s, ks) slice: n*32 + quad*8
    int nOff[4];
    #pragma unroll
    for (int ntl = 0; ntl < 4; ntl++) nOff[ntl] = ((w * 4 + ntl) * 16 + l15) * 32 + quad * 8;
    const int w2Off = l15 * 32 + quad * 8;

    short8* sA = (short8*)smA;

    for (int ks = 0; ks < 32; ++ks) {
        const int k0 = ks * 32;
        // ---- stage A (x splits) into LDS fragment-major [s][kq][row][8] ----
        #pragma unroll
        for (int s = 0; s < 3; s++) {
            const short8 v = *(const short8*)(XS + s * XSZ + (b0 + srow) * D_MODEL + k0 + skq * 8);
            sA[(s * 4 + skq) * 64 + srow] = v;
        }
        __syncthreads();
        // ---- B frags from global (L2-resident) ----
        short8 bfrag[3][4];
        #pragma unroll
        for (int s = 0; s < 3; s++) {
            const unsigned short* base = WPS + ((long)(s * 64 + r) * 32 + ks) * 8192;
            #pragma unroll
            for (int ntl = 0; ntl < 4; ntl++)
                bfrag[s][ntl] = *(const short8*)(base + nOff[ntl]);
        }
        short8 w2f[2];
        #pragma unroll
        for (int s = 0; s < 2; s++)
            w2f[s] = *(const short8*)(WX + ((long)(s * 64 + r) * 32 + ks) * 512 + w2Off);
        // ---- MFMA ----
        #pragma unroll
        for (int mt = 0; mt < 4; mt++) {
            const short8 a0 = sA[(0 * 4 + quad) * 64 + mt * 16 + l15];
            const short8 a1 = sA[(1 * 4 + quad) * 64 + mt * 16 + l15];
            const short8 a2 = sA[(2 * 4 + quad) * 64 + mt * 16 + l15];
            #pragma unroll
            for (int ntl = 0; ntl < 4; ntl++) {
                f32x4 c = acc[mt][ntl];
                c = MFMA_BF16(a0, bfrag[0][ntl], c, 0, 0, 0);
                c = MFMA_BF16(a0, bfrag[1][ntl], c, 0, 0, 0);
                c = MFMA_BF16(a1, bfrag[0][ntl], c, 0, 0, 0);
                c = MFMA_BF16(a0, bfrag[2][ntl], c, 0, 0, 0);
                c = MFMA_BF16(a1, bfrag[1][ntl], c, 0, 0, 0);
                c = MFMA_BF16(a2, bfrag[0][ntl], c, 0, 0, 0);
                acc[mt][ntl] = c;
            }
            if ((mt >> 1) == mtPair) {
                const int mi = mt & 1;
                f32x4 c2 = acc2[mi];
                c2 = MFMA_BF16(a0, w2f[0], c2, 0, 0, 0);
                c2 = MFMA_BF16(a0, w2f[1], c2, 0, 0, 0);
                c2 = MFMA_BF16(a1, w2f[0], c2, 0, 0, 0);
                acc2[mi] = c2;
            }
        }
        __syncthreads();
    }

    // ---- persist diag/alpha pre-activations (C/D: row=quad*4+q, col=l15) ----
    {
        float* arr = isAlpha ? aval : dval;
        #pragma unroll
        for (int mi = 0; mi < 2; mi++) {
            #pragma unroll
            for (int q = 0; q < 4; q++) {
                const int row = (mtPair * 2 + mi) * 16 + quad * 4 + q;
                arr[row * 16 + l15] = acc2[mi][q];
            }
        }
    }
    // ---- stage h, zero h_permuted ----
    #pragma unroll
    for (int q = 0; q < 4; q++) {
        const int id  = t + 256 * q;
        const int row = id >> 4, j = id & 15;
        hv[id]  = h[(long)(b0 + row) * D_MODEL + r * BDIM + j];
        hpm[id] = 0.f;
    }
    __syncthreads();

    // ---- sinkhorn + argmax + scatter, two halves of 32 matrices ----
    for (int half = 0; half < 2; ++half) {
        #pragma unroll
        for (int mi = 0; mi < 2; mi++) {
            const int mt = half * 2 + mi;
            #pragma unroll
            for (int ntl = 0; ntl < 4; ntl++) {
                #pragma unroll
                for (int q = 0; q < 4; q++) {
                    const int ml = mi * 16 + quad * 4 + q;          // row within half
                    la[ml * 272 + (w * 4 + ntl) * 17 + l15] = acc[mt][ntl][q] * 2.0f; // /TAU
                }
            }
        }
        __syncthreads();

        for (int it = 0; it < 5; ++it) {
            #pragma unroll
            for (int q = 0; q < 2; q++) {
                const int id = t + 256 * q;
                const int m = id >> 4, i = id & 15;
                float* rowp = la + m * 272 + i * 17;
                float mx = rowp[0];
                #pragma unroll
                for (int j = 1; j < 16; j++) mx = fmaxf(mx, rowp[j]);
                float s = 0.f;
                #pragma unroll
                for (int j = 0; j < 16; j++) s += expf(rowp[j] - mx);
                const float lse = mx + logf(s);
                #pragma unroll
                for (int j = 0; j < 16; j++) rowp[j] -= lse;
            }
            __syncthreads();
            #pragma unroll
            for (int q = 0; q < 2; q++) {
                const int id = t + 256 * q;
                const int m = id >> 4, j = id & 15;
                float* colp = la + m * 272 + j;
                float mx = colp[0];
                #pragma unroll
                for (int i = 1; i < 16; i++) mx = fmaxf(mx, colp[i * 17]);
                float s = 0.f;
                #pragma unroll
                for (int i = 0; i < 16; i++) s += expf(colp[i * 17] - mx);
                const float lse = mx + logf(s);
                #pragma unroll
                for (int i = 0; i < 16; i++) colp[i * 17] -= lse;
            }
            __syncthreads();
        }
        #pragma unroll
        for (int q = 0; q < 2; q++) {
            const int id = t + 256 * q;
            const int m = id >> 4, j = id & 15;
            const float* colp = la + m * 272 + j;
            float best = colp[0]; int bi = 0;
            #pragma unroll
            for (int i = 1; i < 16; i++) {
                const float v = colp[i * 17];
                if (v > best) { best = v; bi = i; }
            }
            const int gm = half * 32 + m;
            atomicAdd(&hpm[gm * 16 + bi], hv[gm * 16 + j]);
        }
        __syncthreads();
    }

    // ---- final: out = sigmoid(A) * tanh(D) * h_permuted ----
    #pragma unroll
    for (int q = 0; q < 4; q++) {
        const int id  = t + 256 * q;
        const int row = id >> 4, i = id & 15;
        const float A  = aval[id];
        const float Dv = dval[id];
        const float sg = 1.0f / (1.0f + expf(-A));
        out[(long)(b0 + row) * D_MODEL + r * BDIM + i] = sg * tanhf(Dv) * hpm[id];
    }
}

// ---------------- fallback: round-1 fp32 kernel (used if ws too small) ------
__global__ __launch_bounds__(256, 2)
void bmf_fused_kernel(const float* __restrict__ x,
                      const float* __restrict__ h,
                      const float* __restrict__ Wp,
                      const float* __restrict__ Wd,
                      const float* __restrict__ Wa,
                      float* __restrict__ out)
{
    __shared__ float sm[15488];
    float* xs   = sm;
    float* wsh  = sm + 32 * XS_LD;
    float* w2s  = wsh + 32 * 256;
    float* la   = sm;
    float* dval = sm + 11392;
    float* aval = dval + 1024;
    float* hv   = aval + 1024;
    float* hpm  = hv + 1024;

    const int t   = threadIdx.x;
    const int bid = blockIdx.x;
    const int r   = bid >> 5;
    const int b0  = (bid & 31) * MB;
    const long rcol0 = (long)r * (BDIM * BDIM);

    const int tr  = t >> 5;
    const int tc  = t & 31;
    const int cAi = tc * 4;
    const int cBi = 128 + tc * 4;
    const int row2 = t >> 2;
    const int c2   = (t & 3) * 8;

    float acc[8][8];
    float acc2[8];
    #pragma unroll
    for (int i = 0; i < 8; i++) {
        acc2[i] = 0.f;
        #pragma unroll
        for (int j = 0; j < 8; j++) acc[i][j] = 0.f;
    }

    for (int ks = 0; ks < D_MODEL / 32; ++ks) {
        const int k0 = ks * 32;
        {
            const int row = t >> 2, kq = t & 3;
            #pragma unroll
            for (int e = 0; e < 2; e++) {
                const int kk = kq * 4 + e * 16;
                const float4 g = *(const float4*)(x + (long)(b0 + row) * D_MODEL + k0 + kk);
                xs[(kk + 0) * XS_LD + row] = g.x;
                xs[(kk + 1) * XS_LD + row] = g.y;
                xs[(kk + 2) * XS_LD + row] = g.z;
                xs[(kk + 3) * XS_LD + row] = g.w;
            }
        }
        {
            const int rbase = t >> 6;
            const int colf  = (t & 63) * 4;
            #pragma unroll
            for (int rep = 0; rep < 8; rep++) {
                const int rowk = rbase + rep * 4;
                const float4 g = *(const float4*)(Wp + (long)(k0 + rowk) * (RDIM * BDIM * BDIM) + rcol0 + colf);
                *(float4*)(wsh + rowk * 256 + colf) = g;
            }
        }
        {
            const int kr = t >> 3;
            const int c  = (t & 7) * 4;
            const float* src = (c < 16)
                ? (Wd + (long)(k0 + kr) * D_MODEL + r * BDIM + c)
                : (Wa + (long)(k0 + kr) * D_MODEL + r * BDIM + (c - 16));
            const float4 g = *(const float4*)src;
            *(float4*)(w2s + kr * 32 + c) = g;
        }
        __syncthreads();
        #pragma unroll
        for (int kk = 0; kk < 32; ++kk) {
            const float4 xlo = *(const float4*)(xs + kk * XS_LD + tr * 8);
            const float4 xhi = *(const float4*)(xs + kk * XS_LD + tr * 8 + 4);
            const float4 wA  = *(const float4*)(wsh + kk * 256 + cAi);
            const float4 wB  = *(const float4*)(wsh + kk * 256 + cBi);
            const float xv[8] = {xlo.x, xlo.y, xlo.z, xlo.w, xhi.x, xhi.y, xhi.z, xhi.w};
            #pragma unroll
            for (int ri = 0; ri < 8; ri++) {
                acc[ri][0] += xv[ri] * wA.x; acc[ri][1] += xv[ri] * wA.y;
                acc[ri][2] += xv[ri] * wA.z; acc[ri][3] += xv[ri] * wA.w;
                acc[ri][4] += xv[ri] * wB.x; acc[ri][5] += xv[ri] * wB.y;
                acc[ri][6] += xv[ri] * wB.z; acc[ri][7] += xv[ri] * wB.w;
            }
            const float xv2 = xs[kk * XS_LD + row2];
            const float4 u0 = *(const float4*)(w2s + kk * 32 + c2);
            const float4 u1 = *(const float4*)(w2s + kk * 32 + c2 + 4);
            acc2[0] += xv2 * u0.x; acc2[1] += xv2 * u0.y;
            acc2[2] += xv2 * u0.z; acc2[3] += xv2 * u0.w;
            acc2[4] += xv2 * u1.x; acc2[5] += xv2 * u1.y;
            acc2[6] += xv2 * u1.z; acc2[7] += xv2 * u1.w;
        }
        __syncthreads();
    }

    #pragma unroll
    for (int e = 0; e < 8; e++) {
        const int c = c2 + e;
        if (c < 16) dval[row2 * 16 + c] = acc2[e];
        else        aval[row2 * 16 + (c - 16)] = acc2[e];
    }
    #pragma unroll
    for (int q = 0; q < 4; q++) {
        const int id  = t + 256 * q;
        const int row = id >> 4, j = id & 15;
        hv[id]  = h[(long)(b0 + row) * D_MODEL + r * BDIM + j];
        hpm[id] = 0.f;
    }
    __syncthreads();

    for (int half = 0; half < 2; ++half) {
        if ((tr >> 2) == half) {
            const int mbase = (tr & 3) * 8;
            #pragma unroll
            for (int ri = 0; ri < 8; ri++) {
                const int m = mbase + ri;
                #pragma unroll
                for (int e = 0; e < 8; e++) {
                    const int col = (e < 4) ? (cAi + e) : (cBi + e - 4);
                    la[m * 272 + (col >> 4) * 17 + (col & 15)] = acc[ri][e] * 2.0f;
                }
            }
        }
        __syncthreads();

        for (int it = 0; it < 5; ++it) {
            #pragma unroll
            for (int q = 0; q < 2; q++) {
                const int id = t + 256 * q;
                const int m = id >> 4, i = id & 15;
                float* rowp = la + m * 272 + i * 17;
                float mx = rowp[0];
                #pragma unroll
                for (int j = 1; j < 16; j++) mx = fmaxf(mx, rowp[j]);
                float s = 0.f;
                #pragma unroll
                for (int j = 0; j < 16; j++) s += expf(rowp[j] - mx);
                const float lse = mx + logf(s);
                #pragma unroll
                for (int j = 0; j < 16; j++) rowp[j] -= lse;
            }
            __syncthreads();
            #pragma unroll
            for (int q = 0; q < 2; q++) {
                const int id = t + 256 * q;
                const int m = id >> 4, j = id & 15;
                float* colp = la + m * 272 + j;
                float mx = colp[0];
                #pragma unroll
                for (int i = 1; i < 16; i++) mx = fmaxf(mx, colp[i * 17]);
                float s = 0.f;
                #pragma unroll
                for (int i = 0; i < 16; i++) s += expf(colp[i * 17] - mx);
                const float lse = mx + logf(s);
                #pragma unroll
                for (int i = 0; i < 16; i++) colp[i * 17] -= lse;
            }
            __syncthreads();
        }
        #pragma unroll
        for (int q = 0; q < 2; q++) {
            const int id = t + 256 * q;
            const int m = id >> 4, j = id & 15;
            const float* colp = la + m * 272 + j;
            float best = colp[0]; int bi = 0;
            #pragma unroll
            for (int i = 1; i < 16; i++) {
                const float v = colp[i * 17];
                if (v > best) { best = v; bi = i; }
            }
            const int gm = half * 32 + m;
            atomicAdd(&hpm[gm * 16 + bi], hv[gm * 16 + j]);
        }
        __syncthreads();
    }

    #pragma unroll
    for (int q = 0; q < 4; q++) {
        const int id  = t + 256 * q;
        const int row = id >> 4, i = id & 15;
        const float A  = aval[id];
        const float Dv = dval[id];
        const float sg = 1.0f / (1.0f + expf(-A));
        out[(long)(b0 + row) * D_MODEL + r * BDIM + i] = sg * tanhf(Dv) * hpm[id];
    }
}

extern "C" void kernel_launch(void* const* d_in, const int* in_sizes, int n_in,
                              void* d_out, int out_size, void* d_ws, size_t ws_size,
                              hipStream_t stream) {
    const float* x  = (const float*)d_in[0];
    const float* h  = (const float*)d_in[1];
    const float* Wp = (const float*)d_in[2];
    const float* Wd = (const float*)d_in[3];
    const float* Wa = (const float*)d_in[4];
    float* out = (float*)d_out;

    if (ws_size >= (size_t)WS_NEED) {
        unsigned short* XS  = (unsigned short*)((char*)d_ws + OFF_XS);
        unsigned short* WPS = (unsigned short*)((char*)d_ws + OFF_WPS);
        unsigned short* WDS = (unsigned short*)((char*)d_ws + OFF_WDS);
        unsigned short* WAS = (unsigned short*)((char*)d_ws + OFF_WAS);
        k_split_x<<<dim3(XSZ / 256), dim3(256), 0, stream>>>(x, XS);
        k_split_w<<<dim3(256, 32), dim3(256), 0, stream>>>(Wp, WPS, 16384, 256, 3);
        k_split_w<<<dim3(16, 32),  dim3(256), 0, stream>>>(Wd, WDS, 1024, 16, 2);
        k_split_w<<<dim3(16, 32),  dim3(256), 0, stream>>>(Wa, WAS, 1024, 16, 2);
        bmf_mfma_kernel<<<dim3(2048), dim3(256), 0, stream>>>(XS, WPS, WDS, WAS, h, out);
    } else {
        bmf_fused_kernel<<<dim3(2048), dim3(256), 0, stream>>>(x, h, Wp, Wd, Wa, out);
    }
}